// Round 1
// baseline (681.986 us; speedup 1.0000x reference)
//
#include <hip/hip_runtime.h>
#include <hip/hip_fp16.h>

#define T_STEPS 2048
#define BATCH 16
#define DIMD 1024
#define NSTATE 1024
#define MROWS (T_STEPS * BATCH)   // 32768
#define NCH (BATCH * NSTATE)      // 16384

typedef _Float16 f16x8 __attribute__((ext_vector_type(8)));
typedef float f32x4 __attribute__((ext_vector_type(4)));

#define GAS(p) ((const __attribute__((address_space(1))) void*)(p))
#define LAS(p) ((__attribute__((address_space(3))) void*)(p))

// ---------------- f32 -> f16 convert, 8 elements/thread ----------------
__global__ void cvt_kernel(const float* __restrict__ src, _Float16* __restrict__ dst, int n8) {
  int i = blockIdx.x * blockDim.x + threadIdx.x;
  if (i >= n8) return;
  const float4* s4 = (const float4*)src;
  float4 a = s4[(size_t)i * 2];
  float4 b = s4[(size_t)i * 2 + 1];
  f16x8 o;
  o[0] = (_Float16)a.x; o[1] = (_Float16)a.y; o[2] = (_Float16)a.z; o[3] = (_Float16)a.w;
  o[4] = (_Float16)b.x; o[5] = (_Float16)b.y; o[6] = (_Float16)b.z; o[7] = (_Float16)b.w;
  *((f16x8*)dst + i) = o;
}

// ---------------- GEMM: C[m][n] = sum_d A[m][d] * W[n][d]  (NT layout) ----------------
// 128x128 tile, BK=32, 4 waves (2x2), 16x16x32 f16 MFMA, global_load_lds staging.
__global__ void gemm_kernel(const _Float16* __restrict__ A,
                            const _Float16* __restrict__ Wcat,
                            float* __restrict__ Cout) {
  __shared__ _Float16 As[128 * 32];
  __shared__ _Float16 Bs[128 * 32];
  const int tid = threadIdx.x;
  const int lane = tid & 63;
  const int wid = tid >> 6;
  const int wm = wid >> 1;   // 0..1
  const int wn = wid & 1;    // 0..1
  const int tileN = blockIdx.x;   // 0..7
  const int tileM = blockIdx.y;   // 0..255
  const int mat = blockIdx.z;     // 0..2  (k, v, q)

  const _Float16* Ag = A + (size_t)tileM * 128 * DIMD;
  const _Float16* Bg = Wcat + (size_t)mat * NSTATE * DIMD + (size_t)tileN * 128 * DIMD;
  float* C = Cout + (size_t)mat * MROWS * NSTATE;

  f32x4 acc[4][4];
#pragma unroll
  for (int m = 0; m < 4; ++m)
#pragma unroll
    for (int n = 0; n < 4; ++n)
      acc[m][n] = (f32x4){0.f, 0.f, 0.f, 0.f};

  const int srow = tid >> 2;         // 0..63 (staging row within 64-row half)
  const int scolh = (tid & 3) * 8;   // halves offset within BK=32

  for (int kt = 0; kt < DIMD; kt += 32) {
#pragma unroll
    for (int i = 0; i < 2; ++i) {
      // LDS dest = wave-uniform base + lane*16 (linear [128][32] f16, row-major)
      __builtin_amdgcn_global_load_lds(GAS(Ag + (size_t)(srow + i * 64) * DIMD + kt + scolh),
                                       LAS(As + (i * 256 + tid) * 8), 16, 0, 0);
      __builtin_amdgcn_global_load_lds(GAS(Bg + (size_t)(srow + i * 64) * DIMD + kt + scolh),
                                       LAS(Bs + (i * 256 + tid) * 8), 16, 0, 0);
    }
    __syncthreads();   // compiler drains vmcnt(0) before barrier -> LDS ready

    const int fr = lane & 15;
    const int fk = (lane >> 4) * 8;
    f16x8 af[4], bf[4];
#pragma unroll
    for (int m = 0; m < 4; ++m)
      af[m] = *(const f16x8*)(As + (wm * 64 + m * 16 + fr) * 32 + fk);
#pragma unroll
    for (int n = 0; n < 4; ++n)
      bf[n] = *(const f16x8*)(Bs + (wn * 64 + n * 16 + fr) * 32 + fk);

#pragma unroll
    for (int m = 0; m < 4; ++m)
#pragma unroll
      for (int n = 0; n < 4; ++n)
        acc[m][n] = __builtin_amdgcn_mfma_f32_16x16x32_f16(af[m], bf[n], acc[m][n], 0, 0, 0);
    __syncthreads();   // all waves done reading LDS before next stage
  }

  // epilogue: C/D layout col = lane&15, row = (lane>>4)*4 + j  [measured m89]
  const int r4 = (lane >> 4) * 4;
  const int cc = lane & 15;
  const size_t crow0 = (size_t)tileM * 128 + wm * 64;
  const int ccol0 = tileN * 128 + wn * 64;
#pragma unroll
  for (int m = 0; m < 4; ++m)
#pragma unroll
    for (int n = 0; n < 4; ++n)
#pragma unroll
      for (int j = 0; j < 4; ++j)
        C[(crow0 + m * 16 + r4 + j) * NSTATE + ccol0 + n * 16 + cc] = acc[m][n][j];
}

// ---------------- per-row 1/(||k||+eps) ----------------
__global__ void rownorm_kernel(const float* __restrict__ K, float* __restrict__ rnorm) {
  const int r = blockIdx.x;   // 0..32767
  const float4* row = (const float4*)(K + (size_t)r * NSTATE);
  float4 v = row[threadIdx.x];   // 256 threads * 4 = 1024
  float s = v.x * v.x + v.y * v.y + v.z * v.z + v.w * v.w;
#pragma unroll
  for (int off = 32; off > 0; off >>= 1) s += __shfl_down(s, off);
  __shared__ float wsum[4];
  if ((threadIdx.x & 63) == 0) wsum[threadIdx.x >> 6] = s;
  __syncthreads();
  if (threadIdx.x == 0) {
    float tot = wsum[0] + wsum[1] + wsum[2] + wsum[3];
    rnorm[r] = 1.f / (sqrtf(tot) + 1e-6f);
  }
}

// ---------------- sequential scan over t, one channel per lane ----------------
#define STILE 8
__global__ __launch_bounds__(64) void scan_kernel(const float* __restrict__ K,
                                                  const float* __restrict__ V,
                                                  const float* __restrict__ Q,
                                                  const float* __restrict__ rn,
                                                  float* __restrict__ out,
                                                  float* __restrict__ sfin) {
  const int c = blockIdx.x * 64 + threadIdx.x;   // 0..16383
  const int b = c >> 10;
  float S = 0.f;
  float ka[STILE], va[STILE], qa[STILE], ra[STILE];
  float kb[STILE], vb[STILE], qb[STILE], rb[STILE];

  auto LD = [&](float* kx, float* vx, float* qx, float* rx, int t0) {
#pragma unroll
    for (int i = 0; i < STILE; ++i) {
      int t = t0 + i;
      t = t < T_STEPS ? t : (T_STEPS - 1);   // clamp: harmless extra loads at tail
      size_t off = (size_t)t * NCH + c;
      kx[i] = K[off];
      vx[i] = V[off];
      qx[i] = Q[off];
      rx[i] = rn[t * BATCH + b];
    }
  };
  auto STEP = [&](const float* kx, const float* vx, const float* qx, const float* rx, int t0) {
#pragma unroll
    for (int i = 0; i < STILE; ++i) {
      float kn = kx[i] * rx[i];
      float aa = S * (1.f - kn * kn) + vx[i] * kn;
      S = tanhf(aa);
      float z = S * qx[i];
      float sg = 1.f / (1.f + __expf(-z));
      out[(size_t)(t0 + i) * NCH + c] = z * z * sg;
    }
  };

  LD(ka, va, qa, ra, 0);
  for (int t0 = 0; t0 < T_STEPS; t0 += 2 * STILE) {
    LD(kb, vb, qb, rb, t0 + STILE);     // prefetch next tile while computing current
    STEP(ka, va, qa, ra, t0);
    LD(ka, va, qa, ra, t0 + 2 * STILE);
    STEP(kb, vb, qb, rb, t0 + STILE);
  }
  sfin[c] = S;
}

extern "C" void kernel_launch(void* const* d_in, const int* in_sizes, int n_in,
                              void* d_out, int out_size, void* d_ws, size_t ws_size,
                              hipStream_t stream) {
  const float* x = (const float*)d_in[0];
  const float* Wk = (const float*)d_in[1];
  const float* Wv = (const float*)d_in[2];
  const float* Wq = (const float*)d_in[3];

  char* ws = (char*)d_ws;
  _Float16* xh = (_Float16*)ws;                               // 32768*1024*2 = 64 MiB
  _Float16* Wh = (_Float16*)(ws + (size_t)67108864);          // 3*1024*1024*2 = 6 MiB
  float* KVQ = (float*)(ws + (size_t)67108864 + 6291456);     // 3*32768*1024*4 = 384 MiB
  float* Kb = KVQ;
  float* Vb = KVQ + (size_t)MROWS * NSTATE;
  float* Qb = Vb + (size_t)MROWS * NSTATE;
  float* rn = (float*)(ws + (size_t)67108864 + 6291456 + 402653184);  // 32768*4

  // converts
  int n8x = MROWS * DIMD / 8;
  cvt_kernel<<<(n8x + 255) / 256, 256, 0, stream>>>(x, xh, n8x);
  int n8w = NSTATE * DIMD / 8;
  cvt_kernel<<<(n8w + 255) / 256, 256, 0, stream>>>(Wk, Wh, n8w);
  cvt_kernel<<<(n8w + 255) / 256, 256, 0, stream>>>(Wv, Wh + (size_t)NSTATE * DIMD, n8w);
  cvt_kernel<<<(n8w + 255) / 256, 256, 0, stream>>>(Wq, Wh + (size_t)2 * NSTATE * DIMD, n8w);

  // k,v,q projections
  gemm_kernel<<<dim3(8, 256, 3), 256, 0, stream>>>(xh, Wh, KVQ);

  // 1/(||k||+eps) per (t,b) row
  rownorm_kernel<<<MROWS, 256, 0, stream>>>(Kb, rn);

  // scan
  float* outp = (float*)d_out;
  scan_kernel<<<NCH / 64, 64, 0, stream>>>(Kb, Vb, Qb, rn, outp, outp + (size_t)MROWS * NSTATE);
}